// Round 9
// baseline (318.877 us; speedup 1.0000x reference)
//
#include <hip/hip_runtime.h>
#include <hip/hip_bf16.h>
#include <hip/hip_fp16.h>
#include <math.h>

#define N_ATOMS 5000
#define N_EDGES 100000
#define F 128
#define B 20
#define NL 3
#define CAP 64

constexpr float CUTOFF = 5.0f;
constexpr float PI_F = 3.14159265358979323846f;

typedef _Float16 f16x8 __attribute__((ext_vector_type(8)));
typedef _Float16 h2 __attribute__((ext_vector_type(2)));
typedef float f32x4 __attribute__((ext_vector_type(4)));

struct EMeta { int src; float env; };             // 8 B (unit lives in rbf slot)
struct __align__(4) U3 { unsigned int x, y, z; }; // 12 B pv record

__device__ __forceinline__ float silu_f(float x) { return x / (1.0f + __expf(-x)); }

// pv layout: per (atom, t): [phi0, phi1, phi2, v0, v1, v2] f16 (12 B)
#define PV_IDX(atom, t) (((size_t)(atom) * F + (t)) * 6)

// ================================================================ prep kernel
// block ranges: [0,2500) init | [2500,2891) edge bucket+meta+rbf (coalesced edge reads)
//               | [2891, 2891+nb) LDS-tiled weight transpose
#define NB_INIT 2500
#define NB_BUCK 391

struct TPlanT { const float* src; _Float16* dst; int R, C, pad, blk0, tpc; };
struct TPlansT { TPlanT p[22]; int n; };

__global__ __launch_bounds__(256) void prep_kernel(
    const int* __restrict__ Z, const float* __restrict__ emb,
    float* __restrict__ s, _Float16* __restrict__ s_h,
    _Float16* __restrict__ pv,
    const int* __restrict__ eidx, const float* __restrict__ ediff,
    const float* __restrict__ edist,
    int* __restrict__ count, EMeta* __restrict__ meta, _Float16* __restrict__ rbfh,
    TPlansT P) {
    __shared__ float tile[32][33];
    int b = blockIdx.x, tid = threadIdx.x;
    if (b < NB_INIT) {
        int atom = b * 2 + (tid >> 7);
        int t = tid & 127;
        float val = emb[Z[atom] * F + t];
        s[(size_t)atom * F + t] = val;
        s_h[(size_t)atom * F + t] = (_Float16)val;
        // zero v slots (words 1,2); phi slots overwritten by phi kernel for all atoms
        unsigned int* pp = (unsigned int*)(pv + PV_IDX(atom, t));
        pp[1] = 0u; pp[2] = 0u;
        return;
    }
    if (b < NB_INIT + NB_BUCK) {
        // edge-parallel: coalesced reads of eidx/edist/ediff; scattered 56 B slot write
        int e = (b - NB_INIT) * 256 + tid;
        if (e < N_EDGES) {
            int dst = eidx[2 * e];
            int srcA = eidx[2 * e + 1];
            int pos = atomicAdd(&count[dst], 1);
            if (pos < CAP) {
                int slot = dst * CAP + pos;
                float d = edist[e];
                float theta = d * (PI_F / CUTOFF);
                float s1 = __sinf(theta), c1 = __cosf(theta);
                float env = (d < CUTOFF) ? 0.5f * (c1 + 1.0f) : 0.0f;
                float inv = 1.0f / d;
                EMeta mm; mm.src = srcA; mm.env = env;
                meta[slot] = mm;
                _Float16* rp = rbfh + (size_t)slot * 24;
                // sin(k*theta) via Chebyshev recurrence
                float twoc = 2.0f * c1;
                float skm2 = 0.0f, skm1 = s1;
                rp[0] = (_Float16)(s1 * inv);
#pragma unroll
                for (int k = 2; k <= B; ++k) {
                    float sk = twoc * skm1 - skm2;
                    skm2 = skm1; skm1 = sk;
                    rp[k - 1] = (_Float16)(sk * inv);
                }
                rp[20] = (_Float16)(ediff[3 * e + 0] * inv);
                rp[21] = (_Float16)(ediff[3 * e + 1] * inv);
                rp[22] = (_Float16)(ediff[3 * e + 2] * inv);
                rp[23] = (_Float16)0.0f;
            }
        }
        return;
    }
    // ---- tiled transpose: read coalesced, write f16 rows contiguous
    int tb = b - (NB_INIT + NB_BUCK);
    int pi = 0;
#pragma unroll
    for (int i = 1; i < 22; ++i)
        if (i < P.n && tb >= P.p[i].blk0) pi = i;
    const float* src = P.p[pi].src;
    _Float16* dst = P.p[pi].dst;
    int R = P.p[pi].R, C = P.p[pi].C, pad = P.p[pi].pad;
    int tl = tb - P.p[pi].blk0;
    int tpc = P.p[pi].tpc;
    int tr0 = (tl / tpc) * 32, tc0 = (tl % tpc) * 32;
    int i = tid >> 5, j = tid & 31;
#pragma unroll
    for (int rr = 0; rr < 4; ++rr) {
        int r = tr0 + i + 8 * rr, c = tc0 + j;
        if (r < R && c < C) tile[i + 8 * rr][j] = src[(size_t)r * C + c];
    }
    __syncthreads();
#pragma unroll
    for (int rr = 0; rr < 4; ++rr) {
        int c = tc0 + i + 8 * rr, r = tr0 + j;
        if (c < C && r < R) dst[(size_t)c * pad + r] = (_Float16)tile[j][i + 8 * rr];
    }
}

// ================================================================ phi(layer0) MLP
__global__ __launch_bounds__(256) void phi_kernel(
    const _Float16* __restrict__ s_h, const _Float16* __restrict__ w1T,
    const float* __restrict__ b1, const _Float16* __restrict__ w2T,
    const float* __restrict__ b2, _Float16* __restrict__ pv) {
    __shared__ __align__(16) _Float16 shA[16 * 136];
    __shared__ __align__(16) _Float16 shH[16 * 136];
    int r0 = blockIdx.x * 16;
    int tid = threadIdx.x;
    {
        int r = tid >> 4, c8 = (tid & 15) * 8;
        int rg = r0 + r; if (rg >= N_ATOMS) rg = N_ATOMS - 1;
        *(f16x8*)(shA + r * 136 + c8) = *(const f16x8*)(s_h + (size_t)rg * F + c8);
    }
    __syncthreads();
    int lane = tid & 63, wv = tid >> 6;
    int col = lane & 15, quad = lane >> 4;
    for (int nt = wv; nt < 8; nt += 4) {
        int n = nt * 16 + col;
        f32x4 acc = {0.f, 0.f, 0.f, 0.f};
#pragma unroll
        for (int kt = 0; kt < 4; ++kt) {
            f16x8 afr = *(const f16x8*)(shA + col * 136 + kt * 32 + quad * 8);
            f16x8 bfr = *(const f16x8*)(w1T + (size_t)n * 128 + kt * 32 + quad * 8);
            acc = __builtin_amdgcn_mfma_f32_16x16x32_f16(afr, bfr, acc, 0, 0, 0);
        }
        float bb = b1[n];
#pragma unroll
        for (int r = 0; r < 4; ++r)
            shH[(quad * 4 + r) * 136 + n] = (_Float16)silu_f(acc[r] + bb);
    }
    __syncthreads();
    for (int nt = wv; nt < 24; nt += 4) {
        int n = nt * 16 + col;
        f32x4 acc = {0.f, 0.f, 0.f, 0.f};
#pragma unroll
        for (int kt = 0; kt < 4; ++kt) {
            f16x8 afr = *(const f16x8*)(shH + col * 136 + kt * 32 + quad * 8);
            f16x8 bfr = *(const f16x8*)(w2T + (size_t)n * 128 + kt * 32 + quad * 8);
            acc = __builtin_amdgcn_mfma_f32_16x16x32_f16(afr, bfr, acc, 0, 0, 0);
        }
        float bb = b2[n];
#pragma unroll
        for (int r = 0; r < 4; ++r) {
            int row = r0 + quad * 4 + r;
            if (row < N_ATOMS)
                pv[PV_IDX(row, n & 127) + (n >> 7)] = (_Float16)(acc[r] + bb);
        }
    }
}

// ================================================================ per-atom edge aggregation
// proven shape: one block per atom, 256 threads = 2 teams of 128.
// staging: 8 B meta {src,env} + 48 B rbf slot (incl. f16 unit in words 10-11).
__global__ __launch_bounds__(256) void agg_kernel(
    const int* __restrict__ count, const EMeta* __restrict__ meta,
    const _Float16* __restrict__ rbfh,
    const _Float16* __restrict__ fwT, const float* __restrict__ fb,
    const _Float16* __restrict__ pv_r,
    float* __restrict__ s,
    _Float16* __restrict__ vmid_h) {
    int a = blockIdx.x;
    int tid = threadIdx.x;
    int t = tid & 127, team = tid >> 7;

    // hoisted state loads (team 0 only consumes them, issued before staging)
    float s_old = 0.f;
    U3 vq = {0u, 0u, 0u};
    if (team == 0) {
        s_old = s[(size_t)a * F + t];
        vq = *(const U3*)(pv_r + PV_IDX(a, t));
    }

    unsigned int frw0[10], frw1[10], frw2[10];
    {
        const unsigned int* p0 = (const unsigned int*)(fwT + (size_t)t * 24);
        const unsigned int* p1 = (const unsigned int*)(fwT + (size_t)(F + t) * 24);
        const unsigned int* p2 = (const unsigned int*)(fwT + (size_t)(2 * F + t) * 24);
#pragma unroll
        for (int j = 0; j < 10; ++j) { frw0[j] = p0[j]; frw1[j] = p1[j]; frw2[j] = p2[j]; }
    }
    float fb0 = fb[t], fb1 = fb[F + t], fb2 = fb[2 * F + t];

    __shared__ int sh_src[CAP];
    __shared__ float sh_env[CAP];
    __shared__ __align__(16) unsigned int sh_rbf[CAP * 12];
    __shared__ float sh_part[4][F];

    int n = count[a]; if (n > CAP) n = CAP;
    const size_t aC = (size_t)a * CAP;
    if (tid < n) {
        const uint2 mp = *(const uint2*)(meta + aC + tid);
        sh_src[tid] = (int)mp.x;
        sh_env[tid] = __builtin_bit_cast(float, mp.y);
    }
    const unsigned int* rbf32 = (const unsigned int*)rbfh;
    for (int task = tid; task < n * 12; task += 256) {
        int i = task / 12, w = task - i * 12;
        sh_rbf[i * 12 + w] = rbf32[(aC + i) * 12 + w];
    }
    __syncthreads();

    float accS = 0.f, accV0 = 0.f, accV1 = 0.f, accV2 = 0.f;
    int myCnt = (n > team) ? ((n - team + 1) >> 1) : 0;
    if (myCnt > 0) {
        U3 QA[4], QB[4];
        int ngrp = (myCnt + 3) >> 2;
        auto load_grp = [&](int gbase, U3 Q[4]) {
#pragma unroll
            for (int j = 0; j < 4; ++j) {
                int i = gbase + j;
                int ii = (i < myCnt) ? i : (myCnt - 1);
                int src = sh_src[team + 2 * ii];
                Q[j] = *(const U3*)(pv_r + PV_IDX(src, t));
            }
        };
        auto comp_grp = [&](int gbase, U3 Q[4]) {
#pragma unroll
            for (int j = 0; j < 4; ++j) {
                int i = gbase + j;
                if (i < myCnt) {
                    int ei = team + 2 * i;
                    const uint4* rq = (const uint4*)(sh_rbf + ei * 12);
                    uint4 qa = rq[0], qb = rq[1];
                    uint4 qc = rq[2];   // words 8,9 = rbf; 10,11 = unit f16
                    unsigned int rr[10] = {qa.x, qa.y, qa.z, qa.w,
                                           qb.x, qb.y, qb.z, qb.w, qc.x, qc.y};
                    float f0 = fb0, f1 = fb1, f2 = fb2;
#pragma unroll
                    for (int p = 0; p < 10; ++p) {
                        h2 rb = __builtin_bit_cast(h2, rr[p]);
                        f0 = __builtin_amdgcn_fdot2(rb, __builtin_bit_cast(h2, frw0[p]), f0, false);
                        f1 = __builtin_amdgcn_fdot2(rb, __builtin_bit_cast(h2, frw1[p]), f1, false);
                        f2 = __builtin_amdgcn_fdot2(rb, __builtin_bit_cast(h2, frw2[p]), f2, false);
                    }
                    float env = sh_env[ei];
                    f0 *= env; f1 *= env; f2 *= env;
                    h2 u01 = __builtin_bit_cast(h2, qc.z);    // u0, u1
                    h2 u2p = __builtin_bit_cast(h2, qc.w);    // u2, 0
                    h2 q0 = __builtin_bit_cast(h2, Q[j].x);   // phi0, phi1
                    h2 q1 = __builtin_bit_cast(h2, Q[j].y);   // phi2, v0
                    h2 q2 = __builtin_bit_cast(h2, Q[j].z);   // v1, v2
                    accS += f2 * (float)q1[0];
                    float gsv = f0 * (float)q0[0];
                    float gev = f1 * (float)q0[1];
                    accV0 += (float)q1[1] * gsv + gev * (float)u01[0];
                    accV1 += (float)q2[0] * gsv + gev * (float)u01[1];
                    accV2 += (float)q2[1] * gsv + gev * (float)u2p[0];
                }
            }
        };
        load_grp(0, QA);
        for (int g = 0; g < ngrp; g += 2) {
            if (g + 1 < ngrp) load_grp((g + 1) * 4, QB);
            comp_grp(g * 4, QA);
            if (g + 1 < ngrp) {
                if (g + 2 < ngrp) load_grp((g + 2) * 4, QA);
                comp_grp((g + 1) * 4, QB);
            }
        }
    }

    if (team == 1) {
        sh_part[0][t] = accS; sh_part[1][t] = accV0;
        sh_part[2][t] = accV1; sh_part[3][t] = accV2;
    }
    __syncthreads();
    if (team == 0) {
        h2 v1h = __builtin_bit_cast(h2, vq.y);   // phi2, v0
        h2 v2h = __builtin_bit_cast(h2, vq.z);   // v1, v2
        float sm = s_old + accS + sh_part[0][t];
        s[(size_t)a * F + t] = sm;
        float vm0 = (float)v1h[1] + accV0 + sh_part[1][t];
        float vm1 = (float)v2h[0] + accV1 + sh_part[2][t];
        float vm2 = (float)v2h[1] + accV2 + sh_part[3][t];
        vmid_h[(size_t)(a * 3 + 0) * F + t] = (_Float16)vm0;
        vmid_h[(size_t)(a * 3 + 1) * F + t] = (_Float16)vm1;
        vmid_h[(size_t)(a * 3 + 2) * F + t] = (_Float16)vm2;
    }
}

// ================================================================ fused update, TA=16, 512 threads
__global__ __launch_bounds__(512) void fused_update_kernel(
    const _Float16* __restrict__ vmid_h, const _Float16* __restrict__ uvT,
    const _Float16* __restrict__ w1T, const float* __restrict__ b1,
    const _Float16* __restrict__ w2T, const float* __restrict__ b2,
    float* __restrict__ s, _Float16* __restrict__ pv_w,
    const _Float16* __restrict__ nw1T, const float* __restrict__ nb1,
    const _Float16* __restrict__ nw2T, const float* __restrict__ nb2,
    int do_phi,
    const _Float16* __restrict__ roT16, const float* __restrict__ rb1,
    const float* __restrict__ ro_w2p, const float* __restrict__ rb2,
    float* __restrict__ out, int do_ro) {
    __shared__ __align__(16) _Float16 shA[48 * 136];    // vmid tile (stays live through stage 5)
    __shared__ __align__(16) _Float16 shUV[48 * 264];
    __shared__ __align__(16) _Float16 shCat[16 * 264];  // concat; reused as shS after stage 3
    __shared__ __align__(16) _Float16 shH[16 * 136];
    __shared__ __align__(16) _Float16 shAa[16 * 392];
    _Float16* shS = shCat;        // new s tile (16x136 within shCat region)
    float* shRO = (float*)shAa;   // 16 x 68 f32 (alias, used only in do_ro after barrier)
    int a0 = blockIdx.x * 16;
    int r0 = a0 * 3;
    int tid = threadIdx.x;
    for (int slot = tid; slot < 48 * 16; slot += 512) {
        int r = slot >> 4, c8 = (slot & 15) * 8;
        int rg = r0 + r; if (rg >= N_ATOMS * 3) rg = N_ATOMS * 3 - 1;
        *(f16x8*)(shA + r * 136 + c8) = *(const f16x8*)(vmid_h + (size_t)rg * F + c8);
    }
    __syncthreads();
    int lane = tid & 63, wv = tid >> 6;   // wv in [0,8)
    int col = lane & 15, quad = lane >> 4;

    // stage 1: UV = vmid @ [U|V]
    for (int j = wv; j < 48; j += 8) {
        int mt = j >> 4, nt = j & 15;
        int n = nt * 16 + col;
        f32x4 acc = {0.f, 0.f, 0.f, 0.f};
#pragma unroll
        for (int kt = 0; kt < 4; ++kt) {
            f16x8 afr = *(const f16x8*)(shA + (mt * 16 + col) * 136 + kt * 32 + quad * 8);
            f16x8 bfr = *(const f16x8*)(uvT + (size_t)n * 128 + kt * 32 + quad * 8);
            acc = __builtin_amdgcn_mfma_f32_16x16x32_f16(afr, bfr, acc, 0, 0, 0);
        }
#pragma unroll
        for (int r = 0; r < 4; ++r)
            shUV[(mt * 16 + quad * 4 + r) * 264 + n] = (_Float16)acc[r];
    }
    __syncthreads();

    // stage 2: concat = [s, Vn]
    for (int p = tid; p < 2048; p += 512) {
        int ai = p >> 7, t = p & 127;
        int atom = a0 + ai;
        int ag = (atom < N_ATOMS) ? atom : N_ATOMS - 1;
        shCat[ai * 264 + t] = (_Float16)s[(size_t)ag * F + t];
        float x0 = (float)shUV[(ai * 3 + 0) * 264 + 128 + t];
        float x1 = (float)shUV[(ai * 3 + 1) * 264 + 128 + t];
        float x2 = (float)shUV[(ai * 3 + 2) * 264 + 128 + t];
        shCat[ai * 264 + 128 + t] = (_Float16)sqrtf(x0 * x0 + x1 * x1 + x2 * x2);
    }
    __syncthreads();

    // stage 3: hidden = silu(concat @ w1 + b1), K=256
    for (int nt = wv; nt < 8; nt += 8) {
        int n = nt * 16 + col;
        f32x4 acc = {0.f, 0.f, 0.f, 0.f};
#pragma unroll
        for (int kt = 0; kt < 8; ++kt) {
            f16x8 afr = *(const f16x8*)(shCat + col * 264 + kt * 32 + quad * 8);
            f16x8 bfr = *(const f16x8*)(w1T + (size_t)n * 256 + kt * 32 + quad * 8);
            acc = __builtin_amdgcn_mfma_f32_16x16x32_f16(afr, bfr, acc, 0, 0, 0);
        }
        float bb = b1[n];
#pragma unroll
        for (int r = 0; r < 4; ++r)
            shH[(quad * 4 + r) * 136 + n] = (_Float16)silu_f(acc[r] + bb);
    }
    __syncthreads();

    // stage 4: a = hidden @ w2 + b2
    for (int nt = wv; nt < 24; nt += 8) {
        int n = nt * 16 + col;
        f32x4 acc = {0.f, 0.f, 0.f, 0.f};
#pragma unroll
        for (int kt = 0; kt < 4; ++kt) {
            f16x8 afr = *(const f16x8*)(shH + col * 136 + kt * 32 + quad * 8);
            f16x8 bfr = *(const f16x8*)(w2T + (size_t)n * 128 + kt * 32 + quad * 8);
            acc = __builtin_amdgcn_mfma_f32_16x16x32_f16(afr, bfr, acc, 0, 0, 0);
        }
        float bb = b2[n];
#pragma unroll
        for (int r = 0; r < 4; ++r)
            shAa[(quad * 4 + r) * 392 + n] = (_Float16)(acc[r] + bb);
    }
    __syncthreads();

    // stage 5: final elementwise update; vmid base from LDS shA (still live);
    // new s written into shS (= shCat region, dead after stage 3)
    for (int p = tid; p < 2048; p += 512) {
        int ai = p >> 7, t = p & 127;
        int atom = a0 + ai;
        if (atom >= N_ATOMS) { shS[ai * 136 + t] = (_Float16)0.0f; continue; }
        float avv = (float)shAa[ai * 392 + t];
        float asv = (float)shAa[ai * 392 + 128 + t];
        float ass = (float)shAa[ai * 392 + 256 + t];
        float dot = 0.f;
        _Float16* pvp = pv_w + PV_IDX(atom, t);
#pragma unroll
        for (int d = 0; d < 3; ++d) {
            float u = (float)shUV[(ai * 3 + d) * 264 + t];
            float w = (float)shUV[(ai * 3 + d) * 264 + 128 + t];
            dot += u * w;
            float base = (float)shA[(ai * 3 + d) * 136 + t];
            float nv = base + avv * u;
            pvp[3 + d] = (_Float16)nv;
        }
        float sn = s[(size_t)atom * F + t] + asv * dot + ass;
        s[(size_t)atom * F + t] = sn;
        shS[ai * 136 + t] = (_Float16)sn;
    }

    // stage 6a: next layer's phi -> pv_w[0..2]
    if (do_phi) {
        __syncthreads();
        for (int nt = wv; nt < 8; nt += 8) {
            int n = nt * 16 + col;
            f32x4 acc = {0.f, 0.f, 0.f, 0.f};
#pragma unroll
            for (int kt = 0; kt < 4; ++kt) {
                f16x8 afr = *(const f16x8*)(shS + col * 136 + kt * 32 + quad * 8);
                f16x8 bfr = *(const f16x8*)(nw1T + (size_t)n * 128 + kt * 32 + quad * 8);
                acc = __builtin_amdgcn_mfma_f32_16x16x32_f16(afr, bfr, acc, 0, 0, 0);
            }
            float bb = nb1[n];
#pragma unroll
            for (int r = 0; r < 4; ++r)
                shH[(quad * 4 + r) * 136 + n] = (_Float16)silu_f(acc[r] + bb);
        }
        __syncthreads();
        for (int nt = wv; nt < 24; nt += 8) {
            int n = nt * 16 + col;
            f32x4 acc = {0.f, 0.f, 0.f, 0.f};
#pragma unroll
            for (int kt = 0; kt < 4; ++kt) {
                f16x8 afr = *(const f16x8*)(shH + col * 136 + kt * 32 + quad * 8);
                f16x8 bfr = *(const f16x8*)(nw2T + (size_t)n * 128 + kt * 32 + quad * 8);
                acc = __builtin_amdgcn_mfma_f32_16x16x32_f16(afr, bfr, acc, 0, 0, 0);
            }
            float bb = nb2[n];
#pragma unroll
            for (int r = 0; r < 4; ++r) {
                int row = a0 + quad * 4 + r;
                if (row < N_ATOMS)
                    pv_w[PV_IDX(row, n & 127) + (n >> 7)] = (_Float16)(acc[r] + bb);
            }
        }
    }

    // stage 6b: readout (last layer)
    if (do_ro) {
        __syncthreads();
        if (wv < 4) {
            int n = wv * 16 + col;   // n in [0,64)
            f32x4 acc = {0.f, 0.f, 0.f, 0.f};
#pragma unroll
            for (int kt = 0; kt < 4; ++kt) {
                f16x8 afr = *(const f16x8*)(shS + col * 136 + kt * 32 + quad * 8);
                f16x8 bfr = *(const f16x8*)(roT16 + (size_t)n * 128 + kt * 32 + quad * 8);
                acc = __builtin_amdgcn_mfma_f32_16x16x32_f16(afr, bfr, acc, 0, 0, 0);
            }
            float bb = rb1[n], w2n = ro_w2p[n];
#pragma unroll
            for (int r = 0; r < 4; ++r)
                shRO[(quad * 4 + r) * 68 + n] = silu_f(acc[r] + bb) * w2n;
        }
        __syncthreads();
        if (tid < 16) {
            int atom = a0 + tid;
            if (atom < N_ATOMS) {
                float sum = rb2[0];
#pragma unroll 8
                for (int k = 0; k < 64; ++k) sum += shRO[tid * 68 + k];
                out[atom] = sum;
            }
        }
    }
}

// ================================================================ host
extern "C" void kernel_launch(void* const* d_in, const int* in_sizes, int n_in,
                              void* d_out, int out_size, void* d_ws, size_t ws_size,
                              hipStream_t stream) {
    const int*   Z      = (const int*)d_in[0];
    const int*   eidx   = (const int*)d_in[1];
    const float* ediff  = (const float*)d_in[2];
    const float* edist  = (const float*)d_in[3];
    const float* emb    = (const float*)d_in[4];
    const float* msg_w1 = (const float*)d_in[5];
    const float* msg_b1 = (const float*)d_in[6];
    const float* msg_w2 = (const float*)d_in[7];
    const float* msg_b2 = (const float*)d_in[8];
    const float* filt_w = (const float*)d_in[9];
    const float* filt_b = (const float*)d_in[10];
    const float* upd_U  = (const float*)d_in[11];
    const float* upd_V  = (const float*)d_in[12];
    const float* upd_w1 = (const float*)d_in[13];
    const float* upd_b1 = (const float*)d_in[14];
    const float* upd_w2 = (const float*)d_in[15];
    const float* upd_b2 = (const float*)d_in[16];
    const float* ro_w1  = (const float*)d_in[17];
    const float* ro_b1  = (const float*)d_in[18];
    const float* ro_w2  = (const float*)d_in[19];
    const float* ro_b2  = (const float*)d_in[20];
    float* out = (float*)d_out;

    // ---------------- workspace layout ----------------
    float* ws = (float*)d_ws;
    float* s   = ws;                                           // N*F f32
    int* count  = (int*)(s + N_ATOMS * F);                     // N
    EMeta* meta = (EMeta*)(count + N_ATOMS);                   // N*CAP*8B
    _Float16* rbfh = (_Float16*)(meta + (size_t)N_ATOMS * CAP); // N*CAP*24
    _Float16* s_h  = rbfh + (size_t)N_ATOMS * CAP * 24;        // N*F
    _Float16* vmid_h = s_h + (size_t)N_ATOMS * F;              // N*3F
    _Float16* pvA  = vmid_h + (size_t)N_ATOMS * 3 * F;         // N*F*6
    _Float16* pvB  = pvA + (size_t)N_ATOMS * F * 6;            // N*F*6
    _Float16* wh   = pvB + (size_t)N_ATOMS * F * 6;            // f16 weights

    const int HWL = 16384 + 49152 + 32768 + 32768 + 49152 + 384 * 24;
    _Float16* mw1T = wh;                   // [128][128]
    _Float16* mw2T = wh + 16384;           // [384][128]
    _Float16* uvT  = wh + 65536;           // [256][128]
    _Float16* uw1T = wh + 98304;           // [128][256]
    _Float16* uw2T = wh + 131072;          // [384][128]
    _Float16* fwTl = wh + 180224;          // [384][24]
    _Float16* roT16 = wh + (size_t)NL * HWL;  // [64][128]

    // ---------------- transpose plan (tiled) ----------------
    TPlansT P; int nb = 0, pi = 0;
    auto add = [&](const float* src, _Float16* dst, int R, int C, int pad) {
        int tr = (R + 31) / 32, tc = (C + 31) / 32;
        P.p[pi].src = src; P.p[pi].dst = dst;
        P.p[pi].R = R; P.p[pi].C = C; P.p[pi].pad = pad;
        P.p[pi].blk0 = nb; P.p[pi].tpc = tc;
        nb += tr * tc; ++pi;
    };
    for (int l = 0; l < NL; ++l) {
        add(msg_w1 + l * F * F,     mw1T + (size_t)l * HWL, F, F, F);
        add(msg_w2 + l * F * 3 * F, mw2T + (size_t)l * HWL, F, 3 * F, F);
        add(upd_U  + l * F * F,     uvT  + (size_t)l * HWL, F, F, F);
        add(upd_V  + l * F * F,     uvT  + (size_t)l * HWL + F * F, F, F, F);
        add(upd_w1 + l * 2 * F * F, uw1T + (size_t)l * HWL, 2 * F, F, 2 * F);
        add(upd_w2 + l * F * 3 * F, uw2T + (size_t)l * HWL, F, 3 * F, F);
        add(filt_w + l * B * 3 * F, fwTl + (size_t)l * HWL, B, 3 * F, 24);
    }
    add(ro_w1, roT16, F, 64, F);
    P.n = pi;

    // ---------------- launch (8 dispatches total) ----------------
    (void)hipMemsetAsync(count, 0, N_ATOMS * sizeof(int), stream);

    prep_kernel<<<NB_INIT + NB_BUCK + nb, 256, 0, stream>>>(
        Z, emb, s, s_h, pvA, eidx, ediff, edist, count, meta, rbfh, P);

    const int GB16 = (N_ATOMS + 15) / 16;   // 313
    phi_kernel<<<GB16, 256, 0, stream>>>(
        s_h, mw1T, msg_b1, mw2T, msg_b2, pvA);

    _Float16* pr = pvA;
    _Float16* pw = pvB;
    for (int l = 0; l < NL; ++l) {
        int do_phi = (l + 1 < NL);
        int do_ro = (l == NL - 1);
        int ln = do_phi ? (l + 1) : l;
        agg_kernel<<<N_ATOMS, 256, 0, stream>>>(
            count, meta, rbfh,
            fwTl + (size_t)l * HWL, filt_b + l * 3 * F,
            pr, s, vmid_h);
        fused_update_kernel<<<GB16, 512, 0, stream>>>(
            vmid_h, uvT + (size_t)l * HWL,
            uw1T + (size_t)l * HWL, upd_b1 + l * F,
            uw2T + (size_t)l * HWL, upd_b2 + l * 3 * F,
            s, pw,
            mw1T + (size_t)ln * HWL, msg_b1 + ln * F,
            mw2T + (size_t)ln * HWL, msg_b2 + ln * 3 * F, do_phi,
            roT16, ro_b1, ro_w2, ro_b2, out, do_ro);
        _Float16* tmp = pr; pr = pw; pw = tmp;
    }
}

// Round 10
// 303.774 us; speedup vs baseline: 1.0497x; 1.0497x over previous
//
#include <hip/hip_runtime.h>
#include <hip/hip_bf16.h>
#include <hip/hip_fp16.h>
#include <math.h>

#define N_ATOMS 5000
#define N_EDGES 100000
#define F 128
#define B 20
#define NL 3
#define CAP 64
#define TA 10   // atoms per fused_update block (5000/10 = 500 blocks, exact)

constexpr float CUTOFF = 5.0f;
constexpr float PI_F = 3.14159265358979323846f;

typedef _Float16 f16x8 __attribute__((ext_vector_type(8)));
typedef _Float16 h2 __attribute__((ext_vector_type(2)));
typedef float f32x4 __attribute__((ext_vector_type(4)));

struct EMeta { int src; float env; };             // 8 B (unit lives in rbf slot)
struct __align__(4) U3 { unsigned int x, y, z; }; // 12 B pv record

__device__ __forceinline__ float silu_f(float x) { return x / (1.0f + __expf(-x)); }

// pv layout: per (atom, t): [phi0, phi1, phi2, v0, v1, v2] f16 (12 B)
#define PV_IDX(atom, t) (((size_t)(atom) * F + (t)) * 6)

// ================================================================ prep kernel
// block ranges: [0,2500) init | [2500,2891) edge bucket+meta+rbf (coalesced edge reads)
//               | [2891, 2891+nb) LDS-tiled weight transpose
#define NB_INIT 2500
#define NB_BUCK 391

struct TPlanT { const float* src; _Float16* dst; int R, C, pad, blk0, tpc; };
struct TPlansT { TPlanT p[22]; int n; };

__global__ __launch_bounds__(256) void prep_kernel(
    const int* __restrict__ Z, const float* __restrict__ emb,
    float* __restrict__ s, _Float16* __restrict__ s_h,
    _Float16* __restrict__ pv,
    const int* __restrict__ eidx, const float* __restrict__ ediff,
    const float* __restrict__ edist,
    int* __restrict__ count, EMeta* __restrict__ meta, _Float16* __restrict__ rbfh,
    TPlansT P) {
    __shared__ float tile[32][33];
    int b = blockIdx.x, tid = threadIdx.x;
    if (b < NB_INIT) {
        int atom = b * 2 + (tid >> 7);
        int t = tid & 127;
        float val = emb[Z[atom] * F + t];
        s[(size_t)atom * F + t] = val;
        s_h[(size_t)atom * F + t] = (_Float16)val;
        // zero v slots (words 1,2); phi slots overwritten by phi kernel for all atoms
        unsigned int* pp = (unsigned int*)(pv + PV_IDX(atom, t));
        pp[1] = 0u; pp[2] = 0u;
        return;
    }
    if (b < NB_INIT + NB_BUCK) {
        // edge-parallel: coalesced reads of eidx/edist/ediff; scattered 56 B slot write
        int e = (b - NB_INIT) * 256 + tid;
        if (e < N_EDGES) {
            int dst = eidx[2 * e];
            int srcA = eidx[2 * e + 1];
            int pos = atomicAdd(&count[dst], 1);
            if (pos < CAP) {
                int slot = dst * CAP + pos;
                float d = edist[e];
                float theta = d * (PI_F / CUTOFF);
                float s1 = __sinf(theta), c1 = __cosf(theta);
                float env = (d < CUTOFF) ? 0.5f * (c1 + 1.0f) : 0.0f;
                float inv = 1.0f / d;
                EMeta mm; mm.src = srcA; mm.env = env;
                meta[slot] = mm;
                _Float16* rp = rbfh + (size_t)slot * 24;
                // sin(k*theta) via Chebyshev recurrence
                float twoc = 2.0f * c1;
                float skm2 = 0.0f, skm1 = s1;
                rp[0] = (_Float16)(s1 * inv);
#pragma unroll
                for (int k = 2; k <= B; ++k) {
                    float sk = twoc * skm1 - skm2;
                    skm2 = skm1; skm1 = sk;
                    rp[k - 1] = (_Float16)(sk * inv);
                }
                rp[20] = (_Float16)(ediff[3 * e + 0] * inv);
                rp[21] = (_Float16)(ediff[3 * e + 1] * inv);
                rp[22] = (_Float16)(ediff[3 * e + 2] * inv);
                rp[23] = (_Float16)0.0f;
            }
        }
        return;
    }
    // ---- tiled transpose: read coalesced, write f16 rows contiguous
    int tb = b - (NB_INIT + NB_BUCK);
    int pi = 0;
#pragma unroll
    for (int i = 1; i < 22; ++i)
        if (i < P.n && tb >= P.p[i].blk0) pi = i;
    const float* src = P.p[pi].src;
    _Float16* dst = P.p[pi].dst;
    int R = P.p[pi].R, C = P.p[pi].C, pad = P.p[pi].pad;
    int tl = tb - P.p[pi].blk0;
    int tpc = P.p[pi].tpc;
    int tr0 = (tl / tpc) * 32, tc0 = (tl % tpc) * 32;
    int i = tid >> 5, j = tid & 31;
#pragma unroll
    for (int rr = 0; rr < 4; ++rr) {
        int r = tr0 + i + 8 * rr, c = tc0 + j;
        if (r < R && c < C) tile[i + 8 * rr][j] = src[(size_t)r * C + c];
    }
    __syncthreads();
#pragma unroll
    for (int rr = 0; rr < 4; ++rr) {
        int c = tc0 + i + 8 * rr, r = tr0 + j;
        if (c < C && r < R) dst[(size_t)c * pad + r] = (_Float16)tile[j][i + 8 * rr];
    }
}

// ================================================================ phi(layer0) MLP
__global__ __launch_bounds__(256) void phi_kernel(
    const _Float16* __restrict__ s_h, const _Float16* __restrict__ w1T,
    const float* __restrict__ b1, const _Float16* __restrict__ w2T,
    const float* __restrict__ b2, _Float16* __restrict__ pv) {
    __shared__ __align__(16) _Float16 shA[16 * 136];
    __shared__ __align__(16) _Float16 shH[16 * 136];
    int r0 = blockIdx.x * 16;
    int tid = threadIdx.x;
    {
        int r = tid >> 4, c8 = (tid & 15) * 8;
        int rg = r0 + r; if (rg >= N_ATOMS) rg = N_ATOMS - 1;
        *(f16x8*)(shA + r * 136 + c8) = *(const f16x8*)(s_h + (size_t)rg * F + c8);
    }
    __syncthreads();
    int lane = tid & 63, wv = tid >> 6;
    int col = lane & 15, quad = lane >> 4;
    for (int nt = wv; nt < 8; nt += 4) {
        int n = nt * 16 + col;
        f32x4 acc = {0.f, 0.f, 0.f, 0.f};
#pragma unroll
        for (int kt = 0; kt < 4; ++kt) {
            f16x8 afr = *(const f16x8*)(shA + col * 136 + kt * 32 + quad * 8);
            f16x8 bfr = *(const f16x8*)(w1T + (size_t)n * 128 + kt * 32 + quad * 8);
            acc = __builtin_amdgcn_mfma_f32_16x16x32_f16(afr, bfr, acc, 0, 0, 0);
        }
        float bb = b1[n];
#pragma unroll
        for (int r = 0; r < 4; ++r)
            shH[(quad * 4 + r) * 136 + n] = (_Float16)silu_f(acc[r] + bb);
    }
    __syncthreads();
    for (int nt = wv; nt < 24; nt += 4) {
        int n = nt * 16 + col;
        f32x4 acc = {0.f, 0.f, 0.f, 0.f};
#pragma unroll
        for (int kt = 0; kt < 4; ++kt) {
            f16x8 afr = *(const f16x8*)(shH + col * 136 + kt * 32 + quad * 8);
            f16x8 bfr = *(const f16x8*)(w2T + (size_t)n * 128 + kt * 32 + quad * 8);
            acc = __builtin_amdgcn_mfma_f32_16x16x32_f16(afr, bfr, acc, 0, 0, 0);
        }
        float bb = b2[n];
#pragma unroll
        for (int r = 0; r < 4; ++r) {
            int row = r0 + quad * 4 + r;
            if (row < N_ATOMS)
                pv[PV_IDX(row, n & 127) + (n >> 7)] = (_Float16)(acc[r] + bb);
        }
    }
}

// ================================================================ per-atom edge aggregation
// proven shape: one block per atom, 256 threads = 2 teams of 128.
// staging: 8 B meta {src,env} + 48 B rbf slot (incl. f16 unit in words 10-11).
__global__ __launch_bounds__(256) void agg_kernel(
    const int* __restrict__ count, const EMeta* __restrict__ meta,
    const _Float16* __restrict__ rbfh,
    const _Float16* __restrict__ fwT, const float* __restrict__ fb,
    const _Float16* __restrict__ pv_r,
    float* __restrict__ s,
    _Float16* __restrict__ vmid_h) {
    int a = blockIdx.x;
    int tid = threadIdx.x;
    int t = tid & 127, team = tid >> 7;

    // hoisted state loads (team 0 only consumes them, issued before staging)
    float s_old = 0.f;
    U3 vq = {0u, 0u, 0u};
    if (team == 0) {
        s_old = s[(size_t)a * F + t];
        vq = *(const U3*)(pv_r + PV_IDX(a, t));
    }

    unsigned int frw0[10], frw1[10], frw2[10];
    {
        const unsigned int* p0 = (const unsigned int*)(fwT + (size_t)t * 24);
        const unsigned int* p1 = (const unsigned int*)(fwT + (size_t)(F + t) * 24);
        const unsigned int* p2 = (const unsigned int*)(fwT + (size_t)(2 * F + t) * 24);
#pragma unroll
        for (int j = 0; j < 10; ++j) { frw0[j] = p0[j]; frw1[j] = p1[j]; frw2[j] = p2[j]; }
    }
    float fb0 = fb[t], fb1 = fb[F + t], fb2 = fb[2 * F + t];

    __shared__ int sh_src[CAP];
    __shared__ float sh_env[CAP];
    __shared__ __align__(16) unsigned int sh_rbf[CAP * 12];
    __shared__ float sh_part[4][F];

    int n = count[a]; if (n > CAP) n = CAP;
    const size_t aC = (size_t)a * CAP;
    if (tid < n) {
        const uint2 mp = *(const uint2*)(meta + aC + tid);
        sh_src[tid] = (int)mp.x;
        sh_env[tid] = __builtin_bit_cast(float, mp.y);
    }
    const unsigned int* rbf32 = (const unsigned int*)rbfh;
    for (int task = tid; task < n * 12; task += 256) {
        int i = task / 12, w = task - i * 12;
        sh_rbf[i * 12 + w] = rbf32[(aC + i) * 12 + w];
    }
    __syncthreads();

    float accS = 0.f, accV0 = 0.f, accV1 = 0.f, accV2 = 0.f;
    int myCnt = (n > team) ? ((n - team + 1) >> 1) : 0;
    if (myCnt > 0) {
        U3 QA[4], QB[4];
        int ngrp = (myCnt + 3) >> 2;
        auto load_grp = [&](int gbase, U3 Q[4]) {
#pragma unroll
            for (int j = 0; j < 4; ++j) {
                int i = gbase + j;
                int ii = (i < myCnt) ? i : (myCnt - 1);
                int src = sh_src[team + 2 * ii];
                Q[j] = *(const U3*)(pv_r + PV_IDX(src, t));
            }
        };
        auto comp_grp = [&](int gbase, U3 Q[4]) {
#pragma unroll
            for (int j = 0; j < 4; ++j) {
                int i = gbase + j;
                if (i < myCnt) {
                    int ei = team + 2 * i;
                    const uint4* rq = (const uint4*)(sh_rbf + ei * 12);
                    uint4 qa = rq[0], qb = rq[1];
                    uint4 qc = rq[2];   // words 8,9 = rbf; 10,11 = unit f16
                    unsigned int rr[10] = {qa.x, qa.y, qa.z, qa.w,
                                           qb.x, qb.y, qb.z, qb.w, qc.x, qc.y};
                    float f0 = fb0, f1 = fb1, f2 = fb2;
#pragma unroll
                    for (int p = 0; p < 10; ++p) {
                        h2 rb = __builtin_bit_cast(h2, rr[p]);
                        f0 = __builtin_amdgcn_fdot2(rb, __builtin_bit_cast(h2, frw0[p]), f0, false);
                        f1 = __builtin_amdgcn_fdot2(rb, __builtin_bit_cast(h2, frw1[p]), f1, false);
                        f2 = __builtin_amdgcn_fdot2(rb, __builtin_bit_cast(h2, frw2[p]), f2, false);
                    }
                    float env = sh_env[ei];
                    f0 *= env; f1 *= env; f2 *= env;
                    h2 u01 = __builtin_bit_cast(h2, qc.z);    // u0, u1
                    h2 u2p = __builtin_bit_cast(h2, qc.w);    // u2, 0
                    h2 q0 = __builtin_bit_cast(h2, Q[j].x);   // phi0, phi1
                    h2 q1 = __builtin_bit_cast(h2, Q[j].y);   // phi2, v0
                    h2 q2 = __builtin_bit_cast(h2, Q[j].z);   // v1, v2
                    accS += f2 * (float)q1[0];
                    float gsv = f0 * (float)q0[0];
                    float gev = f1 * (float)q0[1];
                    accV0 += (float)q1[1] * gsv + gev * (float)u01[0];
                    accV1 += (float)q2[0] * gsv + gev * (float)u01[1];
                    accV2 += (float)q2[1] * gsv + gev * (float)u2p[0];
                }
            }
        };
        load_grp(0, QA);
        for (int g = 0; g < ngrp; g += 2) {
            if (g + 1 < ngrp) load_grp((g + 1) * 4, QB);
            comp_grp(g * 4, QA);
            if (g + 1 < ngrp) {
                if (g + 2 < ngrp) load_grp((g + 2) * 4, QA);
                comp_grp((g + 1) * 4, QB);
            }
        }
    }

    if (team == 1) {
        sh_part[0][t] = accS; sh_part[1][t] = accV0;
        sh_part[2][t] = accV1; sh_part[3][t] = accV2;
    }
    __syncthreads();
    if (team == 0) {
        h2 v1h = __builtin_bit_cast(h2, vq.y);   // phi2, v0
        h2 v2h = __builtin_bit_cast(h2, vq.z);   // v1, v2
        float sm = s_old + accS + sh_part[0][t];
        s[(size_t)a * F + t] = sm;
        float vm0 = (float)v1h[1] + accV0 + sh_part[1][t];
        float vm1 = (float)v2h[0] + accV1 + sh_part[2][t];
        float vm2 = (float)v2h[1] + accV2 + sh_part[3][t];
        vmid_h[(size_t)(a * 3 + 0) * F + t] = (_Float16)vm0;
        vmid_h[(size_t)(a * 3 + 1) * F + t] = (_Float16)vm1;
        vmid_h[(size_t)(a * 3 + 2) * F + t] = (_Float16)vm2;
    }
}

// ================================================================ fused update, TA=10, 512 threads
// 500 blocks (5000/10 exact): LDS ~50 KB -> 3 blocks/CU, all resident.
// Max-loaded CU does 2 blocks x (10/16)W = 1.25W vs TA=16's 2.0W (313 blocks @ 2/CU).
__global__ __launch_bounds__(512) void fused_update_kernel(
    const _Float16* __restrict__ vmid_h, const _Float16* __restrict__ uvT,
    const _Float16* __restrict__ w1T, const float* __restrict__ b1,
    const _Float16* __restrict__ w2T, const float* __restrict__ b2,
    float* __restrict__ s, _Float16* __restrict__ pv_w,
    const _Float16* __restrict__ nw1T, const float* __restrict__ nb1,
    const _Float16* __restrict__ nw2T, const float* __restrict__ nb2,
    int do_phi,
    const _Float16* __restrict__ roT16, const float* __restrict__ rb1,
    const float* __restrict__ ro_w2p, const float* __restrict__ rb2,
    float* __restrict__ out, int do_ro) {
    __shared__ __align__(16) _Float16 shA[32 * 136];    // vmid tile rows 0..29 valid
    __shared__ __align__(16) _Float16 shUV[32 * 264];
    __shared__ __align__(16) _Float16 shCat[16 * 264];  // rows 0..9 valid; reused as shS
    __shared__ __align__(16) _Float16 shH[16 * 136];
    __shared__ __align__(16) _Float16 shAa[16 * 392];
    _Float16* shS = shCat;        // new s tile (16x136 within shCat region)
    float* shRO = (float*)shAa;   // 16 x 68 f32 (alias, used only in do_ro after barrier)
    int a0 = blockIdx.x * TA;
    int r0 = a0 * 3;
    int tid = threadIdx.x;
    {   // 32 rows x 16 col-groups = 512 slots, one per thread
        int r = tid >> 4, c8 = (tid & 15) * 8;
        int rg = r0 + r; if (rg >= N_ATOMS * 3) rg = N_ATOMS * 3 - 1;
        *(f16x8*)(shA + r * 136 + c8) = *(const f16x8*)(vmid_h + (size_t)rg * F + c8);
    }
    __syncthreads();
    int lane = tid & 63, wv = tid >> 6;   // wv in [0,8)
    int col = lane & 15, quad = lane >> 4;

    // stage 1: UV = vmid @ [U|V]; 2 M-tiles x 16 N-tiles = 32 jobs
    for (int j = wv; j < 32; j += 8) {
        int mt = j >> 4, nt = j & 15;
        int n = nt * 16 + col;
        f32x4 acc = {0.f, 0.f, 0.f, 0.f};
#pragma unroll
        for (int kt = 0; kt < 4; ++kt) {
            f16x8 afr = *(const f16x8*)(shA + (mt * 16 + col) * 136 + kt * 32 + quad * 8);
            f16x8 bfr = *(const f16x8*)(uvT + (size_t)n * 128 + kt * 32 + quad * 8);
            acc = __builtin_amdgcn_mfma_f32_16x16x32_f16(afr, bfr, acc, 0, 0, 0);
        }
#pragma unroll
        for (int r = 0; r < 4; ++r)
            shUV[(mt * 16 + quad * 4 + r) * 264 + n] = (_Float16)acc[r];
    }
    __syncthreads();

    // stage 2: concat = [s, Vn] (rows 0..9)
    for (int p = tid; p < TA * 128; p += 512) {
        int ai = p >> 7, t = p & 127;
        int atom = a0 + ai;
        shCat[ai * 264 + t] = (_Float16)s[(size_t)atom * F + t];
        float x0 = (float)shUV[(ai * 3 + 0) * 264 + 128 + t];
        float x1 = (float)shUV[(ai * 3 + 1) * 264 + 128 + t];
        float x2 = (float)shUV[(ai * 3 + 2) * 264 + 128 + t];
        shCat[ai * 264 + 128 + t] = (_Float16)sqrtf(x0 * x0 + x1 * x1 + x2 * x2);
    }
    __syncthreads();

    // stage 3: hidden = silu(concat @ w1 + b1), K=256 (tile rows 10..15 garbage, discarded)
    for (int nt = wv; nt < 8; nt += 8) {
        int n = nt * 16 + col;
        f32x4 acc = {0.f, 0.f, 0.f, 0.f};
#pragma unroll
        for (int kt = 0; kt < 8; ++kt) {
            f16x8 afr = *(const f16x8*)(shCat + col * 264 + kt * 32 + quad * 8);
            f16x8 bfr = *(const f16x8*)(w1T + (size_t)n * 256 + kt * 32 + quad * 8);
            acc = __builtin_amdgcn_mfma_f32_16x16x32_f16(afr, bfr, acc, 0, 0, 0);
        }
        float bb = b1[n];
#pragma unroll
        for (int r = 0; r < 4; ++r)
            shH[(quad * 4 + r) * 136 + n] = (_Float16)silu_f(acc[r] + bb);
    }
    __syncthreads();

    // stage 4: a = hidden @ w2 + b2
    for (int nt = wv; nt < 24; nt += 8) {
        int n = nt * 16 + col;
        f32x4 acc = {0.f, 0.f, 0.f, 0.f};
#pragma unroll
        for (int kt = 0; kt < 4; ++kt) {
            f16x8 afr = *(const f16x8*)(shH + col * 136 + kt * 32 + quad * 8);
            f16x8 bfr = *(const f16x8*)(w2T + (size_t)n * 128 + kt * 32 + quad * 8);
            acc = __builtin_amdgcn_mfma_f32_16x16x32_f16(afr, bfr, acc, 0, 0, 0);
        }
        float bb = b2[n];
#pragma unroll
        for (int r = 0; r < 4; ++r)
            shAa[(quad * 4 + r) * 392 + n] = (_Float16)(acc[r] + bb);
    }
    __syncthreads();

    // stage 5: final elementwise update; vmid base from LDS shA (still live);
    // new s written into shS (= shCat region, dead after stage 3)
    for (int p = tid; p < TA * 128; p += 512) {
        int ai = p >> 7, t = p & 127;
        int atom = a0 + ai;
        float avv = (float)shAa[ai * 392 + t];
        float asv = (float)shAa[ai * 392 + 128 + t];
        float ass = (float)shAa[ai * 392 + 256 + t];
        float dot = 0.f;
        _Float16* pvp = pv_w + PV_IDX(atom, t);
#pragma unroll
        for (int d = 0; d < 3; ++d) {
            float u = (float)shUV[(ai * 3 + d) * 264 + t];
            float w = (float)shUV[(ai * 3 + d) * 264 + 128 + t];
            dot += u * w;
            float base = (float)shA[(ai * 3 + d) * 136 + t];
            float nv = base + avv * u;
            pvp[3 + d] = (_Float16)nv;
        }
        float sn = s[(size_t)atom * F + t] + asv * dot + ass;
        s[(size_t)atom * F + t] = sn;
        shS[ai * 136 + t] = (_Float16)sn;
    }

    // stage 6a: next layer's phi -> pv_w[0..2] (tile rows >= TA discarded)
    if (do_phi) {
        __syncthreads();
        for (int nt = wv; nt < 8; nt += 8) {
            int n = nt * 16 + col;
            f32x4 acc = {0.f, 0.f, 0.f, 0.f};
#pragma unroll
            for (int kt = 0; kt < 4; ++kt) {
                f16x8 afr = *(const f16x8*)(shS + col * 136 + kt * 32 + quad * 8);
                f16x8 bfr = *(const f16x8*)(nw1T + (size_t)n * 128 + kt * 32 + quad * 8);
                acc = __builtin_amdgcn_mfma_f32_16x16x32_f16(afr, bfr, acc, 0, 0, 0);
            }
            float bb = nb1[n];
#pragma unroll
            for (int r = 0; r < 4; ++r)
                shH[(quad * 4 + r) * 136 + n] = (_Float16)silu_f(acc[r] + bb);
        }
        __syncthreads();
        for (int nt = wv; nt < 24; nt += 8) {
            int n = nt * 16 + col;
            f32x4 acc = {0.f, 0.f, 0.f, 0.f};
#pragma unroll
            for (int kt = 0; kt < 4; ++kt) {
                f16x8 afr = *(const f16x8*)(shH + col * 136 + kt * 32 + quad * 8);
                f16x8 bfr = *(const f16x8*)(nw2T + (size_t)n * 128 + kt * 32 + quad * 8);
                acc = __builtin_amdgcn_mfma_f32_16x16x32_f16(afr, bfr, acc, 0, 0, 0);
            }
            float bb = nb2[n];
#pragma unroll
            for (int r = 0; r < 4; ++r) {
                int rowt = quad * 4 + r;
                if (rowt < TA)
                    pv_w[PV_IDX(a0 + rowt, n & 127) + (n >> 7)] = (_Float16)(acc[r] + bb);
            }
        }
    }

    // stage 6b: readout (last layer)
    if (do_ro) {
        __syncthreads();
        if (wv < 4) {
            int n = wv * 16 + col;   // n in [0,64)
            f32x4 acc = {0.f, 0.f, 0.f, 0.f};
#pragma unroll
            for (int kt = 0; kt < 4; ++kt) {
                f16x8 afr = *(const f16x8*)(shS + col * 136 + kt * 32 + quad * 8);
                f16x8 bfr = *(const f16x8*)(roT16 + (size_t)n * 128 + kt * 32 + quad * 8);
                acc = __builtin_amdgcn_mfma_f32_16x16x32_f16(afr, bfr, acc, 0, 0, 0);
            }
            float bb = rb1[n], w2n = ro_w2p[n];
#pragma unroll
            for (int r = 0; r < 4; ++r)
                shRO[(quad * 4 + r) * 68 + n] = silu_f(acc[r] + bb) * w2n;
        }
        __syncthreads();
        if (tid < TA) {
            int atom = a0 + tid;
            float sum = rb2[0];
#pragma unroll 8
            for (int k = 0; k < 64; ++k) sum += shRO[tid * 68 + k];
            out[atom] = sum;
        }
    }
}

// ================================================================ host
extern "C" void kernel_launch(void* const* d_in, const int* in_sizes, int n_in,
                              void* d_out, int out_size, void* d_ws, size_t ws_size,
                              hipStream_t stream) {
    const int*   Z      = (const int*)d_in[0];
    const int*   eidx   = (const int*)d_in[1];
    const float* ediff  = (const float*)d_in[2];
    const float* edist  = (const float*)d_in[3];
    const float* emb    = (const float*)d_in[4];
    const float* msg_w1 = (const float*)d_in[5];
    const float* msg_b1 = (const float*)d_in[6];
    const float* msg_w2 = (const float*)d_in[7];
    const float* msg_b2 = (const float*)d_in[8];
    const float* filt_w = (const float*)d_in[9];
    const float* filt_b = (const float*)d_in[10];
    const float* upd_U  = (const float*)d_in[11];
    const float* upd_V  = (const float*)d_in[12];
    const float* upd_w1 = (const float*)d_in[13];
    const float* upd_b1 = (const float*)d_in[14];
    const float* upd_w2 = (const float*)d_in[15];
    const float* upd_b2 = (const float*)d_in[16];
    const float* ro_w1  = (const float*)d_in[17];
    const float* ro_b1  = (const float*)d_in[18];
    const float* ro_w2  = (const float*)d_in[19];
    const float* ro_b2  = (const float*)d_in[20];
    float* out = (float*)d_out;

    // ---------------- workspace layout ----------------
    float* ws = (float*)d_ws;
    float* s   = ws;                                           // N*F f32
    int* count  = (int*)(s + N_ATOMS * F);                     // N
    EMeta* meta = (EMeta*)(count + N_ATOMS);                   // N*CAP*8B
    _Float16* rbfh = (_Float16*)(meta + (size_t)N_ATOMS * CAP); // N*CAP*24
    _Float16* s_h  = rbfh + (size_t)N_ATOMS * CAP * 24;        // N*F
    _Float16* vmid_h = s_h + (size_t)N_ATOMS * F;              // N*3F
    _Float16* pvA  = vmid_h + (size_t)N_ATOMS * 3 * F;         // N*F*6
    _Float16* pvB  = pvA + (size_t)N_ATOMS * F * 6;            // N*F*6
    _Float16* wh   = pvB + (size_t)N_ATOMS * F * 6;            // f16 weights

    const int HWL = 16384 + 49152 + 32768 + 32768 + 49152 + 384 * 24;
    _Float16* mw1T = wh;                   // [128][128]
    _Float16* mw2T = wh + 16384;           // [384][128]
    _Float16* uvT  = wh + 65536;           // [256][128]
    _Float16* uw1T = wh + 98304;           // [128][256]
    _Float16* uw2T = wh + 131072;          // [384][128]
    _Float16* fwTl = wh + 180224;          // [384][24]
    _Float16* roT16 = wh + (size_t)NL * HWL;  // [64][128]

    // ---------------- transpose plan (tiled) ----------------
    TPlansT P; int nb = 0, pi = 0;
    auto add = [&](const float* src, _Float16* dst, int R, int C, int pad) {
        int tr = (R + 31) / 32, tc = (C + 31) / 32;
        P.p[pi].src = src; P.p[pi].dst = dst;
        P.p[pi].R = R; P.p[pi].C = C; P.p[pi].pad = pad;
        P.p[pi].blk0 = nb; P.p[pi].tpc = tc;
        nb += tr * tc; ++pi;
    };
    for (int l = 0; l < NL; ++l) {
        add(msg_w1 + l * F * F,     mw1T + (size_t)l * HWL, F, F, F);
        add(msg_w2 + l * F * 3 * F, mw2T + (size_t)l * HWL, F, 3 * F, F);
        add(upd_U  + l * F * F,     uvT  + (size_t)l * HWL, F, F, F);
        add(upd_V  + l * F * F,     uvT  + (size_t)l * HWL + F * F, F, F, F);
        add(upd_w1 + l * 2 * F * F, uw1T + (size_t)l * HWL, 2 * F, F, 2 * F);
        add(upd_w2 + l * F * 3 * F, uw2T + (size_t)l * HWL, F, 3 * F, F);
        add(filt_w + l * B * 3 * F, fwTl + (size_t)l * HWL, B, 3 * F, 24);
    }
    add(ro_w1, roT16, F, 64, F);
    P.n = pi;

    // ---------------- launch (8 dispatches total) ----------------
    (void)hipMemsetAsync(count, 0, N_ATOMS * sizeof(int), stream);

    prep_kernel<<<NB_INIT + NB_BUCK + nb, 256, 0, stream>>>(
        Z, emb, s, s_h, pvA, eidx, ediff, edist, count, meta, rbfh, P);

    const int GB16 = (N_ATOMS + 15) / 16;   // 313 (phi blocks)
    phi_kernel<<<GB16, 256, 0, stream>>>(
        s_h, mw1T, msg_b1, mw2T, msg_b2, pvA);

    const int GBU = N_ATOMS / TA;           // 500 update blocks
    _Float16* pr = pvA;
    _Float16* pw = pvB;
    for (int l = 0; l < NL; ++l) {
        int do_phi = (l + 1 < NL);
        int do_ro = (l == NL - 1);
        int ln = do_phi ? (l + 1) : l;
        agg_kernel<<<N_ATOMS, 256, 0, stream>>>(
            count, meta, rbfh,
            fwTl + (size_t)l * HWL, filt_b + l * 3 * F,
            pr, s, vmid_h);
        fused_update_kernel<<<GBU, 512, 0, stream>>>(
            vmid_h, uvT + (size_t)l * HWL,
            uw1T + (size_t)l * HWL, upd_b1 + l * F,
            uw2T + (size_t)l * HWL, upd_b2 + l * 3 * F,
            s, pw,
            mw1T + (size_t)ln * HWL, msg_b1 + ln * F,
            mw2T + (size_t)ln * HWL, msg_b2 + ln * 3 * F, do_phi,
            roT16, ro_b1, ro_w2, ro_b2, out, do_ro);
        _Float16* tmp = pr; pr = pw; pw = tmp;
    }
}

// Round 11
// 301.344 us; speedup vs baseline: 1.0582x; 1.0081x over previous
//
#include <hip/hip_runtime.h>
#include <hip/hip_bf16.h>
#include <hip/hip_fp16.h>
#include <math.h>

#define N_ATOMS 5000
#define N_EDGES 100000
#define F 128
#define B 20
#define NL 3
#define CAP 64
#define TA 10   // atoms per fused_update block (5000/10 = 500 blocks, exact)

constexpr float CUTOFF = 5.0f;
constexpr float PI_F = 3.14159265358979323846f;

typedef _Float16 f16x8 __attribute__((ext_vector_type(8)));
typedef _Float16 h2 __attribute__((ext_vector_type(2)));
typedef float f32x4 __attribute__((ext_vector_type(4)));

struct EMeta { int src; float env; };             // 8 B (unit lives in rbf slot)
struct __align__(4) U3 { unsigned int x, y, z; }; // 12 B pv record

__device__ __forceinline__ float silu_f(float x) { return x / (1.0f + __expf(-x)); }

// pv layout: per (atom, t): [phi0, phi1, phi2, v0, v1, v2] f16 (12 B)
#define PV_IDX(atom, t) (((size_t)(atom) * F + (t)) * 6)

// ================================================================ prep kernel
// block ranges: [0,2500) init | [2500,2891) edge bucket+meta+rbf (coalesced edge reads)
//               | [2891, 2891+nb) LDS-tiled weight transpose
#define NB_INIT 2500
#define NB_BUCK 391

struct TPlanT { const float* src; _Float16* dst; int R, C, pad, blk0, tpc; };
struct TPlansT { TPlanT p[22]; int n; };

__global__ __launch_bounds__(256) void prep_kernel(
    const int* __restrict__ Z, const float* __restrict__ emb,
    float* __restrict__ s, _Float16* __restrict__ s_h,
    _Float16* __restrict__ pv,
    const int* __restrict__ eidx, const float* __restrict__ ediff,
    const float* __restrict__ edist,
    int* __restrict__ count, EMeta* __restrict__ meta, _Float16* __restrict__ rbfh,
    TPlansT P) {
    __shared__ float tile[32][33];
    int b = blockIdx.x, tid = threadIdx.x;
    if (b < NB_INIT) {
        int atom = b * 2 + (tid >> 7);
        int t = tid & 127;
        float val = emb[Z[atom] * F + t];
        s[(size_t)atom * F + t] = val;
        s_h[(size_t)atom * F + t] = (_Float16)val;
        // zero v slots (words 1,2); phi slots overwritten by phi kernel for all atoms
        unsigned int* pp = (unsigned int*)(pv + PV_IDX(atom, t));
        pp[1] = 0u; pp[2] = 0u;
        return;
    }
    if (b < NB_INIT + NB_BUCK) {
        // edge-parallel: coalesced reads of eidx/edist/ediff; 56 B slot write (3x dwordx4 + 8B)
        int e = (b - NB_INIT) * 256 + tid;
        if (e < N_EDGES) {
            int dst = eidx[2 * e];
            int srcA = eidx[2 * e + 1];
            int pos = atomicAdd(&count[dst], 1);
            if (pos < CAP) {
                int slot = dst * CAP + pos;
                float d = edist[e];
                float theta = d * (PI_F / CUTOFF);
                float s1 = __sinf(theta), c1 = __cosf(theta);
                float env = (d < CUTOFF) ? 0.5f * (c1 + 1.0f) : 0.0f;
                float inv = 1.0f / d;
                EMeta mm; mm.src = srcA; mm.env = env;
                meta[slot] = mm;
                // build all 24 halves in registers (static indexing), store as 3x uint4
                float rb[24];
                float twoc = 2.0f * c1;
                float skm2 = 0.0f, skm1 = s1;
                rb[0] = s1 * inv;
#pragma unroll
                for (int k = 2; k <= B; ++k) {
                    float sk = twoc * skm1 - skm2;
                    skm2 = skm1; skm1 = sk;
                    rb[k - 1] = sk * inv;
                }
                rb[20] = ediff[3 * e + 0] * inv;
                rb[21] = ediff[3 * e + 1] * inv;
                rb[22] = ediff[3 * e + 2] * inv;
                rb[23] = 0.0f;
                unsigned int wv[12];
#pragma unroll
                for (int j = 0; j < 12; ++j) {
                    h2 p; p[0] = (_Float16)rb[2 * j]; p[1] = (_Float16)rb[2 * j + 1];
                    wv[j] = __builtin_bit_cast(unsigned int, p);
                }
                uint4* dst4 = (uint4*)(rbfh + (size_t)slot * 24);
                dst4[0] = make_uint4(wv[0], wv[1], wv[2], wv[3]);
                dst4[1] = make_uint4(wv[4], wv[5], wv[6], wv[7]);
                dst4[2] = make_uint4(wv[8], wv[9], wv[10], wv[11]);
            }
        }
        return;
    }
    // ---- tiled transpose: read coalesced, write f16 rows contiguous
    int tb = b - (NB_INIT + NB_BUCK);
    int pi = 0;
#pragma unroll
    for (int i = 1; i < 22; ++i)
        if (i < P.n && tb >= P.p[i].blk0) pi = i;
    const float* src = P.p[pi].src;
    _Float16* dst = P.p[pi].dst;
    int R = P.p[pi].R, C = P.p[pi].C, pad = P.p[pi].pad;
    int tl = tb - P.p[pi].blk0;
    int tpc = P.p[pi].tpc;
    int tr0 = (tl / tpc) * 32, tc0 = (tl % tpc) * 32;
    int i = tid >> 5, j = tid & 31;
#pragma unroll
    for (int rr = 0; rr < 4; ++rr) {
        int r = tr0 + i + 8 * rr, c = tc0 + j;
        if (r < R && c < C) tile[i + 8 * rr][j] = src[(size_t)r * C + c];
    }
    __syncthreads();
#pragma unroll
    for (int rr = 0; rr < 4; ++rr) {
        int c = tc0 + i + 8 * rr, r = tr0 + j;
        if (c < C && r < R) dst[(size_t)c * pad + r] = (_Float16)tile[j][i + 8 * rr];
    }
}

// ================================================================ phi(layer0) MLP
__global__ __launch_bounds__(256) void phi_kernel(
    const _Float16* __restrict__ s_h, const _Float16* __restrict__ w1T,
    const float* __restrict__ b1, const _Float16* __restrict__ w2T,
    const float* __restrict__ b2, _Float16* __restrict__ pv) {
    __shared__ __align__(16) _Float16 shA[16 * 136];
    __shared__ __align__(16) _Float16 shH[16 * 136];
    int r0 = blockIdx.x * 16;
    int tid = threadIdx.x;
    {
        int r = tid >> 4, c8 = (tid & 15) * 8;
        int rg = r0 + r; if (rg >= N_ATOMS) rg = N_ATOMS - 1;
        *(f16x8*)(shA + r * 136 + c8) = *(const f16x8*)(s_h + (size_t)rg * F + c8);
    }
    __syncthreads();
    int lane = tid & 63, wv = tid >> 6;
    int col = lane & 15, quad = lane >> 4;
    for (int nt = wv; nt < 8; nt += 4) {
        int n = nt * 16 + col;
        f32x4 acc = {0.f, 0.f, 0.f, 0.f};
#pragma unroll
        for (int kt = 0; kt < 4; ++kt) {
            f16x8 afr = *(const f16x8*)(shA + col * 136 + kt * 32 + quad * 8);
            f16x8 bfr = *(const f16x8*)(w1T + (size_t)n * 128 + kt * 32 + quad * 8);
            acc = __builtin_amdgcn_mfma_f32_16x16x32_f16(afr, bfr, acc, 0, 0, 0);
        }
        float bb = b1[n];
#pragma unroll
        for (int r = 0; r < 4; ++r)
            shH[(quad * 4 + r) * 136 + n] = (_Float16)silu_f(acc[r] + bb);
    }
    __syncthreads();
    for (int nt = wv; nt < 24; nt += 4) {
        int n = nt * 16 + col;
        f32x4 acc = {0.f, 0.f, 0.f, 0.f};
#pragma unroll
        for (int kt = 0; kt < 4; ++kt) {
            f16x8 afr = *(const f16x8*)(shH + col * 136 + kt * 32 + quad * 8);
            f16x8 bfr = *(const f16x8*)(w2T + (size_t)n * 128 + kt * 32 + quad * 8);
            acc = __builtin_amdgcn_mfma_f32_16x16x32_f16(afr, bfr, acc, 0, 0, 0);
        }
        float bb = b2[n];
#pragma unroll
        for (int r = 0; r < 4; ++r) {
            int row = r0 + quad * 4 + r;
            if (row < N_ATOMS)
                pv[PV_IDX(row, n & 127) + (n >> 7)] = (_Float16)(acc[r] + bb);
        }
    }
}

// ================================================================ per-atom edge aggregation
// proven shape: one block per atom, 256 threads = 2 teams of 128.
// staging: 8 B meta {src,env} + 48 B rbf slot as 3x uint4 (single conditional load).
__global__ __launch_bounds__(256) void agg_kernel(
    const int* __restrict__ count, const EMeta* __restrict__ meta,
    const _Float16* __restrict__ rbfh,
    const _Float16* __restrict__ fwT, const float* __restrict__ fb,
    const _Float16* __restrict__ pv_r,
    float* __restrict__ s,
    _Float16* __restrict__ vmid_h) {
    int a = blockIdx.x;
    int tid = threadIdx.x;
    int t = tid & 127, team = tid >> 7;

    // hoisted state loads (team 0 only consumes them, issued before staging)
    float s_old = 0.f;
    U3 vq = {0u, 0u, 0u};
    if (team == 0) {
        s_old = s[(size_t)a * F + t];
        vq = *(const U3*)(pv_r + PV_IDX(a, t));
    }

    unsigned int frw0[10], frw1[10], frw2[10];
    {
        const unsigned int* p0 = (const unsigned int*)(fwT + (size_t)t * 24);
        const unsigned int* p1 = (const unsigned int*)(fwT + (size_t)(F + t) * 24);
        const unsigned int* p2 = (const unsigned int*)(fwT + (size_t)(2 * F + t) * 24);
#pragma unroll
        for (int j = 0; j < 10; ++j) { frw0[j] = p0[j]; frw1[j] = p1[j]; frw2[j] = p2[j]; }
    }
    float fb0 = fb[t], fb1 = fb[F + t], fb2 = fb[2 * F + t];

    __shared__ int sh_src[CAP];
    __shared__ float sh_env[CAP];
    __shared__ __align__(16) unsigned int sh_rbf[CAP * 12];
    __shared__ float sh_part[4][F];

    int n = count[a]; if (n > CAP) n = CAP;
    const size_t aC = (size_t)a * CAP;
    if (tid < n) {
        const uint2 mp = *(const uint2*)(meta + aC + tid);
        sh_src[tid] = (int)mp.x;
        sh_env[tid] = __builtin_bit_cast(float, mp.y);
    }
    // rbf staging: n*3 <= 192 uint4 tasks < 256 threads -> single conditional copy
    if (tid < n * 3) {
        int i = tid / 3, w = tid - i * 3;
        ((uint4*)sh_rbf)[i * 3 + w] = ((const uint4*)rbfh)[(aC + i) * 3 + w];
    }
    __syncthreads();

    float accS = 0.f, accV0 = 0.f, accV1 = 0.f, accV2 = 0.f;
    int myCnt = (n > team) ? ((n - team + 1) >> 1) : 0;
    if (myCnt > 0) {
        U3 QA[4], QB[4];
        int ngrp = (myCnt + 3) >> 2;
        auto load_grp = [&](int gbase, U3 Q[4]) {
#pragma unroll
            for (int j = 0; j < 4; ++j) {
                int i = gbase + j;
                int ii = (i < myCnt) ? i : (myCnt - 1);
                int src = sh_src[team + 2 * ii];
                Q[j] = *(const U3*)(pv_r + PV_IDX(src, t));
            }
        };
        auto comp_grp = [&](int gbase, U3 Q[4]) {
#pragma unroll
            for (int j = 0; j < 4; ++j) {
                int i = gbase + j;
                if (i < myCnt) {
                    int ei = team + 2 * i;
                    const uint4* rq = (const uint4*)(sh_rbf + ei * 12);
                    uint4 qa = rq[0], qb = rq[1];
                    uint4 qc = rq[2];   // words 8,9 = rbf; 10,11 = unit f16
                    unsigned int rr[10] = {qa.x, qa.y, qa.z, qa.w,
                                           qb.x, qb.y, qb.z, qb.w, qc.x, qc.y};
                    float f0 = fb0, f1 = fb1, f2 = fb2;
#pragma unroll
                    for (int p = 0; p < 10; ++p) {
                        h2 rb = __builtin_bit_cast(h2, rr[p]);
                        f0 = __builtin_amdgcn_fdot2(rb, __builtin_bit_cast(h2, frw0[p]), f0, false);
                        f1 = __builtin_amdgcn_fdot2(rb, __builtin_bit_cast(h2, frw1[p]), f1, false);
                        f2 = __builtin_amdgcn_fdot2(rb, __builtin_bit_cast(h2, frw2[p]), f2, false);
                    }
                    float env = sh_env[ei];
                    f0 *= env; f1 *= env; f2 *= env;
                    h2 u01 = __builtin_bit_cast(h2, qc.z);    // u0, u1
                    h2 u2p = __builtin_bit_cast(h2, qc.w);    // u2, 0
                    h2 q0 = __builtin_bit_cast(h2, Q[j].x);   // phi0, phi1
                    h2 q1 = __builtin_bit_cast(h2, Q[j].y);   // phi2, v0
                    h2 q2 = __builtin_bit_cast(h2, Q[j].z);   // v1, v2
                    accS += f2 * (float)q1[0];
                    float gsv = f0 * (float)q0[0];
                    float gev = f1 * (float)q0[1];
                    accV0 += (float)q1[1] * gsv + gev * (float)u01[0];
                    accV1 += (float)q2[0] * gsv + gev * (float)u01[1];
                    accV2 += (float)q2[1] * gsv + gev * (float)u2p[0];
                }
            }
        };
        load_grp(0, QA);
        for (int g = 0; g < ngrp; g += 2) {
            if (g + 1 < ngrp) load_grp((g + 1) * 4, QB);
            comp_grp(g * 4, QA);
            if (g + 1 < ngrp) {
                if (g + 2 < ngrp) load_grp((g + 2) * 4, QA);
                comp_grp((g + 1) * 4, QB);
            }
        }
    }

    if (team == 1) {
        sh_part[0][t] = accS; sh_part[1][t] = accV0;
        sh_part[2][t] = accV1; sh_part[3][t] = accV2;
    }
    __syncthreads();
    if (team == 0) {
        h2 v1h = __builtin_bit_cast(h2, vq.y);   // phi2, v0
        h2 v2h = __builtin_bit_cast(h2, vq.z);   // v1, v2
        float sm = s_old + accS + sh_part[0][t];
        s[(size_t)a * F + t] = sm;
        float vm0 = (float)v1h[1] + accV0 + sh_part[1][t];
        float vm1 = (float)v2h[0] + accV1 + sh_part[2][t];
        float vm2 = (float)v2h[1] + accV2 + sh_part[3][t];
        vmid_h[(size_t)(a * 3 + 0) * F + t] = (_Float16)vm0;
        vmid_h[(size_t)(a * 3 + 1) * F + t] = (_Float16)vm1;
        vmid_h[(size_t)(a * 3 + 2) * F + t] = (_Float16)vm2;
    }
}

// ================================================================ fused update, TA=10, 512 threads
// 500 blocks (5000/10 exact): LDS ~50 KB -> 3 blocks/CU, all resident.
__global__ __launch_bounds__(512) void fused_update_kernel(
    const _Float16* __restrict__ vmid_h, const _Float16* __restrict__ uvT,
    const _Float16* __restrict__ w1T, const float* __restrict__ b1,
    const _Float16* __restrict__ w2T, const float* __restrict__ b2,
    float* __restrict__ s, _Float16* __restrict__ pv_w,
    const _Float16* __restrict__ nw1T, const float* __restrict__ nb1,
    const _Float16* __restrict__ nw2T, const float* __restrict__ nb2,
    int do_phi,
    const _Float16* __restrict__ roT16, const float* __restrict__ rb1,
    const float* __restrict__ ro_w2p, const float* __restrict__ rb2,
    float* __restrict__ out, int do_ro) {
    __shared__ __align__(16) _Float16 shA[32 * 136];    // vmid tile rows 0..29 valid
    __shared__ __align__(16) _Float16 shUV[32 * 264];
    __shared__ __align__(16) _Float16 shCat[16 * 264];  // rows 0..9 valid; reused as shS
    __shared__ __align__(16) _Float16 shH[16 * 136];
    __shared__ __align__(16) _Float16 shAa[16 * 392];
    _Float16* shS = shCat;        // new s tile (16x136 within shCat region)
    float* shRO = (float*)shAa;   // 16 x 68 f32 (alias, used only in do_ro after barrier)
    int a0 = blockIdx.x * TA;
    int r0 = a0 * 3;
    int tid = threadIdx.x;
    {   // 32 rows x 16 col-groups = 512 slots, one per thread
        int r = tid >> 4, c8 = (tid & 15) * 8;
        int rg = r0 + r; if (rg >= N_ATOMS * 3) rg = N_ATOMS * 3 - 1;
        *(f16x8*)(shA + r * 136 + c8) = *(const f16x8*)(vmid_h + (size_t)rg * F + c8);
    }
    __syncthreads();
    int lane = tid & 63, wv = tid >> 6;   // wv in [0,8)
    int col = lane & 15, quad = lane >> 4;

    // stage 1: UV = vmid @ [U|V]; 2 M-tiles x 16 N-tiles = 32 jobs
    for (int j = wv; j < 32; j += 8) {
        int mt = j >> 4, nt = j & 15;
        int n = nt * 16 + col;
        f32x4 acc = {0.f, 0.f, 0.f, 0.f};
#pragma unroll
        for (int kt = 0; kt < 4; ++kt) {
            f16x8 afr = *(const f16x8*)(shA + (mt * 16 + col) * 136 + kt * 32 + quad * 8);
            f16x8 bfr = *(const f16x8*)(uvT + (size_t)n * 128 + kt * 32 + quad * 8);
            acc = __builtin_amdgcn_mfma_f32_16x16x32_f16(afr, bfr, acc, 0, 0, 0);
        }
#pragma unroll
        for (int r = 0; r < 4; ++r)
            shUV[(mt * 16 + quad * 4 + r) * 264 + n] = (_Float16)acc[r];
    }
    __syncthreads();

    // stage 2: concat = [s, Vn] (rows 0..9)
    for (int p = tid; p < TA * 128; p += 512) {
        int ai = p >> 7, t = p & 127;
        int atom = a0 + ai;
        shCat[ai * 264 + t] = (_Float16)s[(size_t)atom * F + t];
        float x0 = (float)shUV[(ai * 3 + 0) * 264 + 128 + t];
        float x1 = (float)shUV[(ai * 3 + 1) * 264 + 128 + t];
        float x2 = (float)shUV[(ai * 3 + 2) * 264 + 128 + t];
        shCat[ai * 264 + 128 + t] = (_Float16)sqrtf(x0 * x0 + x1 * x1 + x2 * x2);
    }
    __syncthreads();

    // stage 3: hidden = silu(concat @ w1 + b1), K=256 (tile rows 10..15 garbage, discarded)
    for (int nt = wv; nt < 8; nt += 8) {
        int n = nt * 16 + col;
        f32x4 acc = {0.f, 0.f, 0.f, 0.f};
#pragma unroll
        for (int kt = 0; kt < 8; ++kt) {
            f16x8 afr = *(const f16x8*)(shCat + col * 264 + kt * 32 + quad * 8);
            f16x8 bfr = *(const f16x8*)(w1T + (size_t)n * 256 + kt * 32 + quad * 8);
            acc = __builtin_amdgcn_mfma_f32_16x16x32_f16(afr, bfr, acc, 0, 0, 0);
        }
        float bb = b1[n];
#pragma unroll
        for (int r = 0; r < 4; ++r)
            shH[(quad * 4 + r) * 136 + n] = (_Float16)silu_f(acc[r] + bb);
    }
    __syncthreads();

    // stage 4: a = hidden @ w2 + b2
    for (int nt = wv; nt < 24; nt += 8) {
        int n = nt * 16 + col;
        f32x4 acc = {0.f, 0.f, 0.f, 0.f};
#pragma unroll
        for (int kt = 0; kt < 4; ++kt) {
            f16x8 afr = *(const f16x8*)(shH + col * 136 + kt * 32 + quad * 8);
            f16x8 bfr = *(const f16x8*)(w2T + (size_t)n * 128 + kt * 32 + quad * 8);
            acc = __builtin_amdgcn_mfma_f32_16x16x32_f16(afr, bfr, acc, 0, 0, 0);
        }
        float bb = b2[n];
#pragma unroll
        for (int r = 0; r < 4; ++r)
            shAa[(quad * 4 + r) * 392 + n] = (_Float16)(acc[r] + bb);
    }
    __syncthreads();

    // stage 5: final elementwise update; vmid base from LDS shA (still live);
    // new s written into shS (= shCat region, dead after stage 3)
    for (int p = tid; p < TA * 128; p += 512) {
        int ai = p >> 7, t = p & 127;
        int atom = a0 + ai;
        float avv = (float)shAa[ai * 392 + t];
        float asv = (float)shAa[ai * 392 + 128 + t];
        float ass = (float)shAa[ai * 392 + 256 + t];
        float dot = 0.f;
        _Float16* pvp = pv_w + PV_IDX(atom, t);
#pragma unroll
        for (int d = 0; d < 3; ++d) {
            float u = (float)shUV[(ai * 3 + d) * 264 + t];
            float w = (float)shUV[(ai * 3 + d) * 264 + 128 + t];
            dot += u * w;
            float base = (float)shA[(ai * 3 + d) * 136 + t];
            float nv = base + avv * u;
            pvp[3 + d] = (_Float16)nv;
        }
        float sn = s[(size_t)atom * F + t] + asv * dot + ass;
        s[(size_t)atom * F + t] = sn;
        shS[ai * 136 + t] = (_Float16)sn;
    }

    // stage 6a: next layer's phi -> pv_w[0..2] (tile rows >= TA discarded)
    if (do_phi) {
        __syncthreads();
        for (int nt = wv; nt < 8; nt += 8) {
            int n = nt * 16 + col;
            f32x4 acc = {0.f, 0.f, 0.f, 0.f};
#pragma unroll
            for (int kt = 0; kt < 4; ++kt) {
                f16x8 afr = *(const f16x8*)(shS + col * 136 + kt * 32 + quad * 8);
                f16x8 bfr = *(const f16x8*)(nw1T + (size_t)n * 128 + kt * 32 + quad * 8);
                acc = __builtin_amdgcn_mfma_f32_16x16x32_f16(afr, bfr, acc, 0, 0, 0);
            }
            float bb = nb1[n];
#pragma unroll
            for (int r = 0; r < 4; ++r)
                shH[(quad * 4 + r) * 136 + n] = (_Float16)silu_f(acc[r] + bb);
        }
        __syncthreads();
        for (int nt = wv; nt < 24; nt += 8) {
            int n = nt * 16 + col;
            f32x4 acc = {0.f, 0.f, 0.f, 0.f};
#pragma unroll
            for (int kt = 0; kt < 4; ++kt) {
                f16x8 afr = *(const f16x8*)(shH + col * 136 + kt * 32 + quad * 8);
                f16x8 bfr = *(const f16x8*)(nw2T + (size_t)n * 128 + kt * 32 + quad * 8);
                acc = __builtin_amdgcn_mfma_f32_16x16x32_f16(afr, bfr, acc, 0, 0, 0);
            }
            float bb = nb2[n];
#pragma unroll
            for (int r = 0; r < 4; ++r) {
                int rowt = quad * 4 + r;
                if (rowt < TA)
                    pv_w[PV_IDX(a0 + rowt, n & 127) + (n >> 7)] = (_Float16)(acc[r] + bb);
            }
        }
    }

    // stage 6b: readout (last layer)
    if (do_ro) {
        __syncthreads();
        if (wv < 4) {
            int n = wv * 16 + col;   // n in [0,64)
            f32x4 acc = {0.f, 0.f, 0.f, 0.f};
#pragma unroll
            for (int kt = 0; kt < 4; ++kt) {
                f16x8 afr = *(const f16x8*)(shS + col * 136 + kt * 32 + quad * 8);
                f16x8 bfr = *(const f16x8*)(roT16 + (size_t)n * 128 + kt * 32 + quad * 8);
                acc = __builtin_amdgcn_mfma_f32_16x16x32_f16(afr, bfr, acc, 0, 0, 0);
            }
            float bb = rb1[n], w2n = ro_w2p[n];
#pragma unroll
            for (int r = 0; r < 4; ++r)
                shRO[(quad * 4 + r) * 68 + n] = silu_f(acc[r] + bb) * w2n;
        }
        __syncthreads();
        if (tid < TA) {
            int atom = a0 + tid;
            float sum = rb2[0];
#pragma unroll 8
            for (int k = 0; k < 64; ++k) sum += shRO[tid * 68 + k];
            out[atom] = sum;
        }
    }
}

// ================================================================ host
extern "C" void kernel_launch(void* const* d_in, const int* in_sizes, int n_in,
                              void* d_out, int out_size, void* d_ws, size_t ws_size,
                              hipStream_t stream) {
    const int*   Z      = (const int*)d_in[0];
    const int*   eidx   = (const int*)d_in[1];
    const float* ediff  = (const float*)d_in[2];
    const float* edist  = (const float*)d_in[3];
    const float* emb    = (const float*)d_in[4];
    const float* msg_w1 = (const float*)d_in[5];
    const float* msg_b1 = (const float*)d_in[6];
    const float* msg_w2 = (const float*)d_in[7];
    const float* msg_b2 = (const float*)d_in[8];
    const float* filt_w = (const float*)d_in[9];
    const float* filt_b = (const float*)d_in[10];
    const float* upd_U  = (const float*)d_in[11];
    const float* upd_V  = (const float*)d_in[12];
    const float* upd_w1 = (const float*)d_in[13];
    const float* upd_b1 = (const float*)d_in[14];
    const float* upd_w2 = (const float*)d_in[15];
    const float* upd_b2 = (const float*)d_in[16];
    const float* ro_w1  = (const float*)d_in[17];
    const float* ro_b1  = (const float*)d_in[18];
    const float* ro_w2  = (const float*)d_in[19];
    const float* ro_b2  = (const float*)d_in[20];
    float* out = (float*)d_out;

    // ---------------- workspace layout ----------------
    float* ws = (float*)d_ws;
    float* s   = ws;                                           // N*F f32
    int* count  = (int*)(s + N_ATOMS * F);                     // N
    EMeta* meta = (EMeta*)(count + N_ATOMS);                   // N*CAP*8B
    _Float16* rbfh = (_Float16*)(meta + (size_t)N_ATOMS * CAP); // N*CAP*24
    _Float16* s_h  = rbfh + (size_t)N_ATOMS * CAP * 24;        // N*F
    _Float16* vmid_h = s_h + (size_t)N_ATOMS * F;              // N*3F
    _Float16* pvA  = vmid_h + (size_t)N_ATOMS * 3 * F;         // N*F*6
    _Float16* pvB  = pvA + (size_t)N_ATOMS * F * 6;            // N*F*6
    _Float16* wh   = pvB + (size_t)N_ATOMS * F * 6;            // f16 weights

    const int HWL = 16384 + 49152 + 32768 + 32768 + 49152 + 384 * 24;
    _Float16* mw1T = wh;                   // [128][128]
    _Float16* mw2T = wh + 16384;           // [384][128]
    _Float16* uvT  = wh + 65536;           // [256][128]
    _Float16* uw1T = wh + 98304;           // [128][256]
    _Float16* uw2T = wh + 131072;          // [384][128]
    _Float16* fwTl = wh + 180224;          // [384][24]
    _Float16* roT16 = wh + (size_t)NL * HWL;  // [64][128]

    // ---------------- transpose plan (tiled) ----------------
    TPlansT P; int nb = 0, pi = 0;
    auto add = [&](const float* src, _Float16* dst, int R, int C, int pad) {
        int tr = (R + 31) / 32, tc = (C + 31) / 32;
        P.p[pi].src = src; P.p[pi].dst = dst;
        P.p[pi].R = R; P.p[pi].C = C; P.p[pi].pad = pad;
        P.p[pi].blk0 = nb; P.p[pi].tpc = tc;
        nb += tr * tc; ++pi;
    };
    for (int l = 0; l < NL; ++l) {
        add(msg_w1 + l * F * F,     mw1T + (size_t)l * HWL, F, F, F);
        add(msg_w2 + l * F * 3 * F, mw2T + (size_t)l * HWL, F, 3 * F, F);
        add(upd_U  + l * F * F,     uvT  + (size_t)l * HWL, F, F, F);
        add(upd_V  + l * F * F,     uvT  + (size_t)l * HWL + F * F, F, F, F);
        add(upd_w1 + l * 2 * F * F, uw1T + (size_t)l * HWL, 2 * F, F, 2 * F);
        add(upd_w2 + l * F * 3 * F, uw2T + (size_t)l * HWL, F, 3 * F, F);
        add(filt_w + l * B * 3 * F, fwTl + (size_t)l * HWL, B, 3 * F, 24);
    }
    add(ro_w1, roT16, F, 64, F);
    P.n = pi;

    // ---------------- launch (8 dispatches total) ----------------
    (void)hipMemsetAsync(count, 0, N_ATOMS * sizeof(int), stream);

    prep_kernel<<<NB_INIT + NB_BUCK + nb, 256, 0, stream>>>(
        Z, emb, s, s_h, pvA, eidx, ediff, edist, count, meta, rbfh, P);

    const int GB16 = (N_ATOMS + 15) / 16;   // 313 (phi blocks)
    phi_kernel<<<GB16, 256, 0, stream>>>(
        s_h, mw1T, msg_b1, mw2T, msg_b2, pvA);

    const int GBU = N_ATOMS / TA;           // 500 update blocks
    _Float16* pr = pvA;
    _Float16* pw = pvB;
    for (int l = 0; l < NL; ++l) {
        int do_phi = (l + 1 < NL);
        int do_ro = (l == NL - 1);
        int ln = do_phi ? (l + 1) : l;
        agg_kernel<<<N_ATOMS, 256, 0, stream>>>(
            count, meta, rbfh,
            fwTl + (size_t)l * HWL, filt_b + l * 3 * F,
            pr, s, vmid_h);
        fused_update_kernel<<<GBU, 512, 0, stream>>>(
            vmid_h, uvT + (size_t)l * HWL,
            uw1T + (size_t)l * HWL, upd_b1 + l * F,
            uw2T + (size_t)l * HWL, upd_b2 + l * 3 * F,
            s, pw,
            mw1T + (size_t)ln * HWL, msg_b1 + ln * F,
            mw2T + (size_t)ln * HWL, msg_b2 + ln * 3 * F, do_phi,
            roT16, ro_b1, ro_w2, ro_b2, out, do_ro);
        _Float16* tmp = pr; pr = pw; pw = tmp;
    }
}